// Round 1
// baseline (775.847 us; speedup 1.0000x reference)
//
#include <hip/hip_runtime.h>
#include <math.h>

#define D64 64

// ---------------- K1: per-edge scalar stats ----------------
__global__ __launch_bounds__(256) void edge_stats_kernel(
    const int* __restrict__ dst, const float* __restrict__ eig,
    int* __restrict__ deg, float* __restrict__ absum, float* __restrict__ sege, int E)
{
    int e = blockIdx.x * 256 + threadIdx.x;
    if (e < E) {
        int dn = dst[e];
        float w = eig[e];
        atomicAdd(&deg[dn], 1);
        atomicAdd(&absum[dn], fabsf(w));
        atomicAdd(&sege[dn], w);
    }
}

// ---------------- K2a: per-block reduce of deg ----------------
__global__ __launch_bounds__(256) void block_reduce_kernel(
    const int* __restrict__ deg, int* __restrict__ bsum, int N)
{
    __shared__ int sd[256];
    int t = threadIdx.x;
    int i = blockIdx.x * 256 + t;
    sd[t] = (i < N) ? deg[i] : 0;
    __syncthreads();
    for (int s = 128; s > 0; s >>= 1) {
        if (t < s) sd[t] += sd[t + s];
        __syncthreads();
    }
    if (t == 0) bsum[blockIdx.x] = sd[0];
}

// ---------------- K2b: scan block sums (single block) ----------------
__global__ __launch_bounds__(1024) void scan_bsums_kernel(
    const int* __restrict__ bsum, int* __restrict__ bscan, int nb)
{
    __shared__ int sd[1024];
    int t = threadIdx.x;
    int own = (t < nb) ? bsum[t] : 0;
    sd[t] = own;
    __syncthreads();
    for (int off = 1; off < 1024; off <<= 1) {
        int v = (t >= off) ? sd[t - off] : 0;
        __syncthreads();
        sd[t] += v;
        __syncthreads();
    }
    if (t < nb) bscan[t] = sd[t] - own;   // exclusive prefix
}

// ---------------- K2c: per-block exclusive scan -> offsets + cursor ----------------
__global__ __launch_bounds__(256) void block_scan_kernel(
    const int* __restrict__ deg, const int* __restrict__ bscan,
    int* __restrict__ offs, int* __restrict__ cursor, int N)
{
    __shared__ int sd[256];
    int t = threadIdx.x;
    int i = blockIdx.x * 256 + t;
    int myv = (i < N) ? deg[i] : 0;
    sd[t] = myv;
    __syncthreads();
    for (int off = 1; off < 256; off <<= 1) {
        int v = (t >= off) ? sd[t - off] : 0;
        __syncthreads();
        sd[t] += v;
        __syncthreads();
    }
    if (i < N) {
        int ex = sd[t] - myv + bscan[blockIdx.x];
        offs[i] = ex;
        cursor[i] = ex;
    }
}

// ---------------- K3: scatter edges into CSR (by dst) ----------------
__global__ __launch_bounds__(256) void csr_scatter_kernel(
    const int* __restrict__ src, const int* __restrict__ dst, const float* __restrict__ eig,
    int* __restrict__ cursor, int* __restrict__ csr_src, float* __restrict__ csr_eig, int E)
{
    int e = blockIdx.x * 256 + threadIdx.x;
    if (e < E) {
        int dn = dst[e];
        int p = atomicAdd(&cursor[dn], 1);
        csr_src[p] = src[e];
        csr_eig[p] = eig[e];
    }
}

// ---------------- K4: u = h @ A^T ; v = h @ B^T + b1  (A|B = W1 halves) ----------------
// tile: 64 nodes x 128 combined outputs, 256 threads, each 4 nodes x 8 outs
__global__ __launch_bounds__(256) void uv_kernel(
    const float* __restrict__ h, const float* __restrict__ W1, const float* __restrict__ b1,
    float* __restrict__ u, float* __restrict__ v, int N)
{
    __shared__ float wT[64 * 128];   // wT[j*128 + c]
    __shared__ float hs[64 * 68];    // hs[n*68 + j], padded
    int t = threadIdx.x;
    for (int idx = t; idx < 64 * 128; idx += 256) {
        int j = idx >> 7, c = idx & 127;
        int d = c & 63;
        int col = (c < 64) ? j : (64 + j);
        wT[idx] = W1[d * 128 + col];
    }
    int n0 = blockIdx.x * 64;
    for (int r = 0; r < 16; ++r) {
        int idx = r * 256 + t;
        int nl = idx >> 6, j = idx & 63;
        int n = n0 + nl;
        hs[nl * 68 + j] = (n < N) ? h[n * 64 + j] : 0.f;
    }
    __syncthreads();

    int nb = (t & 15) * 4;
    int cb = (t >> 4) * 8;
    float acc[4][8];
#pragma unroll
    for (int i = 0; i < 4; ++i)
#pragma unroll
        for (int k = 0; k < 8; ++k) acc[i][k] = 0.f;

    for (int j = 0; j < 64; ++j) {
        float wv[8];
#pragma unroll
        for (int k = 0; k < 8; ++k) wv[k] = wT[j * 128 + cb + k];
#pragma unroll
        for (int i = 0; i < 4; ++i) {
            float hv = hs[(nb + i) * 68 + j];
#pragma unroll
            for (int k = 0; k < 8; ++k) acc[i][k] = fmaf(hv, wv[k], acc[i][k]);
        }
    }

    bool isV = (cb >= 64);
    int dbase = cb & 63;
#pragma unroll
    for (int i = 0; i < 4; ++i) {
        int n = n0 + nb + i;
        if (n < N) {
            if (!isV) {
#pragma unroll
                for (int k = 0; k < 8; ++k) u[n * 64 + dbase + k] = acc[i][k];
            } else {
#pragma unroll
                for (int k = 0; k < 8; ++k) v[n * 64 + dbase + k] = acc[i][k] + b1[dbase + k];
            }
        }
    }
}

// ---------------- K5: fused aggregation + posttrans + BN partials ----------------
__global__ __launch_bounds__(256) void agg_post_kernel(
    const float* __restrict__ h, const float* __restrict__ u, const float* __restrict__ v,
    const int* __restrict__ offs, const int* __restrict__ degi,
    const float* __restrict__ absum, const float* __restrict__ sege,
    const int* __restrict__ csr_src, const float* __restrict__ csr_eig,
    const float* __restrict__ W2, const float* __restrict__ b2,
    const float* __restrict__ snorm, float* __restrict__ h2,
    float* __restrict__ bn_buf, int N)
{
    __shared__ float hc[256];
    __shared__ float psum[256], pmax[256], pdir[256], ppart[256];
    int t = threadIdx.x;
    int d = t & 63, sg = t >> 6;
    float w2r[64];
#pragma unroll
    for (int j = 0; j < 64; ++j) w2r[j] = W2[d * 256 + sg * 64 + j];
    float b2r = b2[d];
    float bs = 0.f, bq = 0.f;

    for (int n = blockIdx.x; n < N; n += gridDim.x) {
        int beg = offs[n];
        int dn = degi[n];
        float inv_ab = 1.f / (absum[n] + 1e-8f);
        float segw = sege[n] * inv_ab;
        if (t < 64) hc[t] = h[n * 64 + t];

        float accs = 0.f, accd = 0.f, accm = -3.402823466e38f;
        for (int i = beg + sg; i < beg + dn; i += 4) {
            int s = csr_src[i];
            float we = csr_eig[i] * inv_ab;
            float uv = u[s * 64 + d];
            accs += uv;
            accm = fmaxf(accm, uv);
            accd += we * uv;
        }
        psum[t] = accs; pmax[t] = accm; pdir[t] = accd;
        __syncthreads();

        if (t < 64) {
            float s4 = psum[t] + psum[64 + t] + psum[128 + t] + psum[192 + t];
            float m4 = fmaxf(fmaxf(pmax[t], pmax[64 + t]), fmaxf(pmax[128 + t], pmax[192 + t]));
            float d4 = pdir[t] + pdir[64 + t] + pdir[128 + t] + pdir[192 + t];
            float vl = v[n * 64 + t];
            float hl = hc[t];
            float fdeg = (float)dn;
            hc[64 + t]  = (s4 + fdeg * vl) / fmaxf(fdeg, 1.f);
            hc[128 + t] = (dn > 0) ? (m4 + vl) : 0.f;
            hc[192 + t] = fabsf(d4 + segw * vl - segw * hl);
        }
        __syncthreads();

        float part = 0.f;
#pragma unroll
        for (int j = 0; j < 64; ++j) part = fmaf(w2r[j], hc[sg * 64 + j], part);
        ppart[t] = part;
        __syncthreads();

        if (t < 64) {
            float val = (ppart[t] + ppart[64 + t] + ppart[128 + t] + ppart[192 + t] + b2r) * snorm[n];
            h2[n * 64 + t] = val;
            bs += val; bq += val * val;
        }
        __syncthreads();
    }
    if (t < 64) {
        atomicAdd(&bn_buf[t], bs);
        atomicAdd(&bn_buf[64 + t], bq);
    }
}

// ---------------- K6: BN normalize + relu + residual ----------------
__global__ __launch_bounds__(256) void bn_final_kernel(
    const float* __restrict__ h, const float* __restrict__ h2,
    const float* __restrict__ bn_buf, const float* __restrict__ gamma,
    const float* __restrict__ beta, float* __restrict__ out, int N, float invN)
{
    int idx = blockIdx.x * 256 + threadIdx.x;  // one float4 per thread
    int total4 = N * 16;
    if (idx >= total4) return;
    int base = idx * 4;
    int d0 = base & 63;
    const float4 a = *(const float4*)(h2 + base);
    const float4 hh = *(const float4*)(h + base);
    float r[4] = {a.x, a.y, a.z, a.w};
    float hv[4] = {hh.x, hh.y, hh.z, hh.w};
    float o[4];
#pragma unroll
    for (int k = 0; k < 4; ++k) {
        int d = d0 + k;
        float mu = bn_buf[d] * invN;
        float var = bn_buf[64 + d] * invN - mu * mu;
        float rstd = rsqrtf(var + 1e-5f);
        float x = (r[k] - mu) * rstd * gamma[d] + beta[d];
        o[k] = hv[k] + fmaxf(x, 0.f);
    }
    float4 ov = {o[0], o[1], o[2], o[3]};
    *(float4*)(out + base) = ov;
}

// ---------------- launch ----------------
extern "C" void kernel_launch(void* const* d_in, const int* in_sizes, int n_in,
                              void* d_out, int out_size, void* d_ws, size_t ws_size,
                              hipStream_t stream)
{
    const float* h     = (const float*)d_in[0];
    const float* eig   = (const float*)d_in[1];
    const float* snorm = (const float*)d_in[2];
    const int*   src   = (const int*)d_in[3];
    const int*   dst   = (const int*)d_in[4];
    const float* W1    = (const float*)d_in[5];
    const float* b1    = (const float*)d_in[6];
    const float* W2    = (const float*)d_in[7];
    const float* b2    = (const float*)d_in[8];
    const float* gamma = (const float*)d_in[9];
    const float* beta  = (const float*)d_in[10];
    float* out = (float*)d_out;

    const int N = in_sizes[2];
    const int E = in_sizes[1];

    // ---- workspace layout (256B aligned slices) ----
    char* w = (char*)d_ws;
    size_t off = 0;
    auto alloc = [&](size_t bytes) -> char* {
        char* p = w + off;
        off += (bytes + 255) & ~size_t(255);
        return p;
    };
    float* u       = (float*)alloc((size_t)N * 64 * 4);
    float* v       = (float*)alloc((size_t)N * 64 * 4);
    float* h2      = (float*)alloc((size_t)N * 64 * 4);
    float* csr_eig = (float*)alloc((size_t)E * 4);
    int*   csr_src = (int*)alloc((size_t)E * 4);
    // contiguous zero region: deg, absum, sege, bn_buf
    char* zero_base = w + off;
    int*   deg   = (int*)alloc((size_t)N * 4);
    float* absum = (float*)alloc((size_t)N * 4);
    float* sege  = (float*)alloc((size_t)N * 4);
    float* bn_buf= (float*)alloc(128 * 4);
    size_t zero_bytes = (size_t)((char*)(bn_buf + 128) - zero_base);
    int*   offs   = (int*)alloc((size_t)N * 4);
    int*   cursor = (int*)alloc((size_t)N * 4);
    int nb = (N + 255) / 256;
    int*   bsum  = (int*)alloc((size_t)nb * 4);
    int*   bscan = (int*)alloc((size_t)nb * 4);
    (void)ws_size; (void)n_in; (void)out_size;

    hipMemsetAsync(zero_base, 0, zero_bytes, stream);

    int egrid = (E + 255) / 256;
    edge_stats_kernel<<<egrid, 256, 0, stream>>>(dst, eig, deg, absum, sege, E);
    block_reduce_kernel<<<nb, 256, 0, stream>>>(deg, bsum, N);
    scan_bsums_kernel<<<1, 1024, 0, stream>>>(bsum, bscan, nb);
    block_scan_kernel<<<nb, 256, 0, stream>>>(deg, bscan, offs, cursor, N);
    csr_scatter_kernel<<<egrid, 256, 0, stream>>>(src, dst, eig, cursor, csr_src, csr_eig, E);

    int ntiles = (N + 63) / 64;
    uv_kernel<<<ntiles, 256, 0, stream>>>(h, W1, b1, u, v, N);

    agg_post_kernel<<<2048, 256, 0, stream>>>(h, u, v, offs, deg, absum, sege,
                                              csr_src, csr_eig, W2, b2, snorm,
                                              h2, bn_buf, N);

    int fgrid = (N * 16 + 255) / 256;
    bn_final_kernel<<<fgrid, 256, 0, stream>>>(h, h2, bn_buf, gamma, beta, out, N, 1.0f / (float)N);
}

// Round 2
// 570.098 us; speedup vs baseline: 1.3609x; 1.3609x over previous
//
#include <hip/hip_runtime.h>
#include <math.h>

__device__ __forceinline__ float bf2f(unsigned short s) {
    return __uint_as_float(((unsigned)s) << 16);
}
__device__ __forceinline__ unsigned short f2bf(float f) {
    unsigned u = __float_as_uint(f);
    unsigned r = (u + 0x7fffu + ((u >> 16) & 1u)) >> 16;   // RNE
    return (unsigned short)r;
}

// ---------------- K1: per-edge scalar stats ----------------
__global__ __launch_bounds__(256) void edge_stats_kernel(
    const int* __restrict__ dst, const float* __restrict__ eig,
    int* __restrict__ deg, float* __restrict__ absum, float* __restrict__ sege, int E)
{
    int e = blockIdx.x * 256 + threadIdx.x;
    if (e < E) {
        int dn = dst[e];
        float w = eig[e];
        atomicAdd(&deg[dn], 1);
        atomicAdd(&absum[dn], fabsf(w));
        atomicAdd(&sege[dn], w);
    }
}

// ---------------- K2a: per-block reduce of deg ----------------
__global__ __launch_bounds__(256) void block_reduce_kernel(
    const int* __restrict__ deg, int* __restrict__ bsum, int N)
{
    __shared__ int sd[256];
    int t = threadIdx.x;
    int i = blockIdx.x * 256 + t;
    sd[t] = (i < N) ? deg[i] : 0;
    __syncthreads();
    for (int s = 128; s > 0; s >>= 1) {
        if (t < s) sd[t] += sd[t + s];
        __syncthreads();
    }
    if (t == 0) bsum[blockIdx.x] = sd[0];
}

// ---------------- K2b: scan block sums (single block) ----------------
__global__ __launch_bounds__(1024) void scan_bsums_kernel(
    const int* __restrict__ bsum, int* __restrict__ bscan, int nb)
{
    __shared__ int sd[1024];
    int t = threadIdx.x;
    int own = (t < nb) ? bsum[t] : 0;
    sd[t] = own;
    __syncthreads();
    for (int off = 1; off < 1024; off <<= 1) {
        int v = (t >= off) ? sd[t - off] : 0;
        __syncthreads();
        sd[t] += v;
        __syncthreads();
    }
    if (t < nb) bscan[t] = sd[t] - own;   // exclusive prefix
}

// ---------------- K2c: per-block exclusive scan -> offsets + cursor ----------------
__global__ __launch_bounds__(256) void block_scan_kernel(
    const int* __restrict__ deg, const int* __restrict__ bscan,
    int* __restrict__ offs, int* __restrict__ cursor, int N)
{
    __shared__ int sd[256];
    int t = threadIdx.x;
    int i = blockIdx.x * 256 + t;
    int myv = (i < N) ? deg[i] : 0;
    sd[t] = myv;
    __syncthreads();
    for (int off = 1; off < 256; off <<= 1) {
        int v = (t >= off) ? sd[t - off] : 0;
        __syncthreads();
        sd[t] += v;
        __syncthreads();
    }
    if (i < N) {
        int ex = sd[t] - myv + bscan[blockIdx.x];
        offs[i] = ex;
        cursor[i] = ex;
    }
}

// ---------------- K3: scatter edges into CSR (by dst) ----------------
__global__ __launch_bounds__(256) void csr_scatter_kernel(
    const int* __restrict__ src, const int* __restrict__ dst, const float* __restrict__ eig,
    int* __restrict__ cursor, int* __restrict__ csr_src, float* __restrict__ csr_eig, int E)
{
    int e = blockIdx.x * 256 + threadIdx.x;
    if (e < E) {
        int dn = dst[e];
        int p = atomicAdd(&cursor[dn], 1);
        csr_src[p] = src[e];
        csr_eig[p] = eig[e];
    }
}

// ---------------- K4: u = h @ A^T ; v = h @ B^T + b1 (bf16 outputs) ----------------
__global__ __launch_bounds__(256) void uv_kernel(
    const float* __restrict__ h, const float* __restrict__ W1, const float* __restrict__ b1,
    unsigned short* __restrict__ u, unsigned short* __restrict__ v, int N)
{
    __shared__ float wT[64 * 128];   // wT[j*128 + c]
    __shared__ float hs[64 * 68];    // hs[n*68 + j], padded
    int t = threadIdx.x;
    for (int idx = t; idx < 64 * 128; idx += 256) {
        int j = idx >> 7, c = idx & 127;
        int d = c & 63;
        int col = (c < 64) ? j : (64 + j);
        wT[idx] = W1[d * 128 + col];
    }
    int n0 = blockIdx.x * 64;
    for (int r = 0; r < 16; ++r) {
        int idx = r * 256 + t;
        int nl = idx >> 6, j = idx & 63;
        int n = n0 + nl;
        hs[nl * 68 + j] = (n < N) ? h[(size_t)n * 64 + j] : 0.f;
    }
    __syncthreads();

    int nb = (t & 15) * 4;
    int cb = (t >> 4) * 8;
    float acc[4][8];
#pragma unroll
    for (int i = 0; i < 4; ++i)
#pragma unroll
        for (int k = 0; k < 8; ++k) acc[i][k] = 0.f;

    for (int j = 0; j < 64; ++j) {
        float wv[8];
#pragma unroll
        for (int k = 0; k < 8; ++k) wv[k] = wT[j * 128 + cb + k];
#pragma unroll
        for (int i = 0; i < 4; ++i) {
            float hv = hs[(nb + i) * 68 + j];
#pragma unroll
            for (int k = 0; k < 8; ++k) acc[i][k] = fmaf(hv, wv[k], acc[i][k]);
        }
    }

    bool isV = (cb >= 64);
    int dbase = cb & 63;
#pragma unroll
    for (int i = 0; i < 4; ++i) {
        int n = n0 + nb + i;
        if (n < N) {
            union { unsigned short s[8]; uint4 v4; } pk;
            if (!isV) {
#pragma unroll
                for (int k = 0; k < 8; ++k) pk.s[k] = f2bf(acc[i][k]);
                *(uint4*)(u + (size_t)n * 64 + dbase) = pk.v4;
            } else {
#pragma unroll
                for (int k = 0; k < 8; ++k) pk.s[k] = f2bf(acc[i][k] + b1[dbase + k]);
                *(uint4*)(v + (size_t)n * 64 + dbase) = pk.v4;
            }
        }
    }
}

// ---------------- K4b: W2 transpose -> w2t[k][d] ----------------
__global__ __launch_bounds__(256) void w2t_kernel(
    const float* __restrict__ W2, float* __restrict__ w2t)
{
    int idx = blockIdx.x * 256 + threadIdx.x;
    if (idx < 64 * 256) {
        int d = idx >> 8, k = idx & 255;
        w2t[k * 64 + d] = W2[idx];
    }
}

// ---------------- K5: aggregation, one wave per node ----------------
__global__ __launch_bounds__(256) void agg_kernel(
    const unsigned short* __restrict__ u, const unsigned short* __restrict__ v,
    const float* __restrict__ h,
    const int* __restrict__ offs, const int* __restrict__ degi,
    const float* __restrict__ absum, const float* __restrict__ sege,
    const int* __restrict__ csr_src, const float* __restrict__ csr_eig,
    unsigned short* __restrict__ agg, int N)
{
    int gw = (blockIdx.x * 256 + threadIdx.x) >> 6;
    int lane = threadIdx.x & 63;
    int n = __builtin_amdgcn_readfirstlane(gw);
    if (n >= N) return;
    int beg = offs[n];
    int dn = degi[n];
    float inv_ab = 1.f / (absum[n] + 1e-8f);
    float segw = sege[n] * inv_ab;

    float accs = 0.f, accd = 0.f, accm = -3.402823466e38f;
    for (int i0 = 0; i0 < dn; i0 += 64) {
        int cnt = min(dn - i0, 64);
        int idxv = 0; float wvv = 0.f;
        if (lane < cnt) {
            idxv = csr_src[beg + i0 + lane];
            wvv  = csr_eig[beg + i0 + lane];
        }
        int j = 0;
        for (; j + 4 <= cnt; j += 4) {
            int s0 = __shfl(idxv, j), s1 = __shfl(idxv, j + 1);
            int s2 = __shfl(idxv, j + 2), s3 = __shfl(idxv, j + 3);
            float w0 = __shfl(wvv, j), w1 = __shfl(wvv, j + 1);
            float w2_ = __shfl(wvv, j + 2), w3 = __shfl(wvv, j + 3);
            float u0 = bf2f(u[(size_t)s0 * 64 + lane]);
            float u1 = bf2f(u[(size_t)s1 * 64 + lane]);
            float u2 = bf2f(u[(size_t)s2 * 64 + lane]);
            float u3 = bf2f(u[(size_t)s3 * 64 + lane]);
            accs += (u0 + u1) + (u2 + u3);
            accm = fmaxf(accm, fmaxf(fmaxf(u0, u1), fmaxf(u2, u3)));
            accd = fmaf(w0, u0, fmaf(w1, u1, fmaf(w2_, u2, fmaf(w3, u3, accd))));
        }
        for (; j < cnt; ++j) {
            int s0 = __shfl(idxv, j);
            float w0 = __shfl(wvv, j);
            float u0 = bf2f(u[(size_t)s0 * 64 + lane]);
            accs += u0;
            accm = fmaxf(accm, u0);
            accd = fmaf(w0, u0, accd);
        }
    }
    float vl = bf2f(v[(size_t)n * 64 + lane]);
    float hl = h[(size_t)n * 64 + lane];
    float fdeg = (float)dn;
    float mean = (accs + fdeg * vl) / fmaxf(fdeg, 1.f);
    float amax = (dn > 0) ? (accm + vl) : 0.f;
    float adir = fabsf(fmaf(accd, inv_ab, segw * (vl - hl)));
    size_t base = (size_t)n * 192;
    agg[base + lane]       = f2bf(mean);
    agg[base + 64 + lane]  = f2bf(amax);
    agg[base + 128 + lane] = f2bf(adir);
}

// ---------------- K6: posttrans GEMM-T + BN partials ----------------
// thread = node column; 4 waves cover 64 outputs (16/thread); W2T via scalar loads
__global__ __launch_bounds__(256) void post_gemm_kernel(
    const float* __restrict__ h, const unsigned short* __restrict__ agg,
    const float* __restrict__ w2t, const float* __restrict__ b2,
    const float* __restrict__ snorm, float* __restrict__ h2,
    float* __restrict__ bn_buf, int N)
{
    __shared__ float hcS[64 * 65];   // [k][node], stride 65 (conflict-free)
    int tid = threadIdx.x;
    int node = tid & 63;
    int q = __builtin_amdgcn_readfirstlane(tid >> 6);
    int n0 = blockIdx.x * 64;
    int n = n0 + node;
    float acc[16];
#pragma unroll
    for (int i = 0; i < 16; ++i) acc[i] = 0.f;

    for (int c = 0; c < 4; ++c) {
        if (c == 0) {
            // stage h chunk (fp32), transposed into hcS
            for (int it = 0; it < 4; ++it) {
                int idx = it * 256 + tid;     // 0..1023
                int r = idx >> 4, c4 = idx & 15;
                int nn = n0 + r;
                float4 val = make_float4(0.f, 0.f, 0.f, 0.f);
                if (nn < N) val = *(const float4*)(h + (size_t)nn * 64 + c4 * 4);
                int kk = c4 * 4;
                hcS[(kk + 0) * 65 + r] = val.x;
                hcS[(kk + 1) * 65 + r] = val.y;
                hcS[(kk + 2) * 65 + r] = val.z;
                hcS[(kk + 3) * 65 + r] = val.w;
            }
        } else {
            // stage agg chunk (bf16), transposed into hcS
            for (int it = 0; it < 2; ++it) {
                int idx = it * 256 + tid;     // 0..511
                int r = idx >> 3, j8 = idx & 7;
                int nn = n0 + r;
                uint4 val = make_uint4(0, 0, 0, 0);
                if (nn < N) val = *(const uint4*)(agg + (size_t)nn * 192 + (c - 1) * 64 + j8 * 8);
                unsigned short* ps = (unsigned short*)&val;
                int kk = j8 * 8;
#pragma unroll
                for (int m = 0; m < 8; ++m)
                    hcS[(kk + m) * 65 + r] = bf2f(ps[m]);
            }
        }
        __syncthreads();
        const float* wbase = w2t + c * 64 * 64 + q * 16;
        for (int k = 0; k < 64; ++k) {
            float hv = hcS[k * 65 + node];
            const float* wr = wbase + k * 64;
#pragma unroll
            for (int i = 0; i < 16; ++i)
                acc[i] = fmaf(wr[i], hv, acc[i]);
        }
        __syncthreads();
    }

    // epilogue: bias, snorm
    float sn = (n < N) ? snorm[n] : 0.f;
#pragma unroll
    for (int i = 0; i < 16; ++i) acc[i] = (acc[i] + b2[q * 16 + i]) * sn;

    if (n < N) {
#pragma unroll
        for (int i = 0; i < 4; ++i) {
            float4 o = make_float4(acc[i * 4], acc[i * 4 + 1], acc[i * 4 + 2], acc[i * 4 + 3]);
            *(float4*)(h2 + (size_t)n * 64 + q * 16 + i * 4) = o;
        }
    }

    // BN partials: transpose through LDS, per-d block sums -> atomics
#pragma unroll
    for (int i = 0; i < 16; ++i) hcS[(q * 16 + i) * 65 + node] = acc[i];
    __syncthreads();
    if (tid < 64) {
        float s1 = 0.f, s2 = 0.f;
        for (int r = 0; r < 64; ++r) {
            float x = hcS[tid * 65 + r];
            s1 += x;
            s2 = fmaf(x, x, s2);
        }
        atomicAdd(&bn_buf[tid], s1);
        atomicAdd(&bn_buf[64 + tid], s2);
    }
}

// ---------------- K7: BN normalize + relu + residual ----------------
__global__ __launch_bounds__(256) void bn_final_kernel(
    const float* __restrict__ h, const float* __restrict__ h2,
    const float* __restrict__ bn_buf, const float* __restrict__ gamma,
    const float* __restrict__ beta, float* __restrict__ out, int N, float invN)
{
    int idx = blockIdx.x * 256 + threadIdx.x;  // one float4 per thread
    int total4 = N * 16;
    if (idx >= total4) return;
    int base = idx * 4;
    int d0 = base & 63;
    const float4 a = *(const float4*)(h2 + base);
    const float4 hh = *(const float4*)(h + base);
    float r[4] = {a.x, a.y, a.z, a.w};
    float hv[4] = {hh.x, hh.y, hh.z, hh.w};
    float o[4];
#pragma unroll
    for (int k = 0; k < 4; ++k) {
        int d = d0 + k;
        float mu = bn_buf[d] * invN;
        float var = bn_buf[64 + d] * invN - mu * mu;
        float rstd = rsqrtf(var + 1e-5f);
        float x = (r[k] - mu) * rstd * gamma[d] + beta[d];
        o[k] = hv[k] + fmaxf(x, 0.f);
    }
    float4 ov = {o[0], o[1], o[2], o[3]};
    *(float4*)(out + base) = ov;
}

// ---------------- launch ----------------
extern "C" void kernel_launch(void* const* d_in, const int* in_sizes, int n_in,
                              void* d_out, int out_size, void* d_ws, size_t ws_size,
                              hipStream_t stream)
{
    const float* h     = (const float*)d_in[0];
    const float* eig   = (const float*)d_in[1];
    const float* snorm = (const float*)d_in[2];
    const int*   src   = (const int*)d_in[3];
    const int*   dst   = (const int*)d_in[4];
    const float* W1    = (const float*)d_in[5];
    const float* b1    = (const float*)d_in[6];
    const float* W2    = (const float*)d_in[7];
    const float* b2    = (const float*)d_in[8];
    const float* gamma = (const float*)d_in[9];
    const float* beta  = (const float*)d_in[10];
    float* out = (float*)d_out;

    const int N = in_sizes[2];
    const int E = in_sizes[1];

    // ---- workspace layout (256B aligned slices) ----
    char* w = (char*)d_ws;
    size_t off = 0;
    auto alloc = [&](size_t bytes) -> char* {
        char* p = w + off;
        off += (bytes + 255) & ~size_t(255);
        return p;
    };
    // u,v bf16 contiguous (25.6MB); h2 fp32 aliases the same region after agg
    unsigned short* u = (unsigned short*)alloc((size_t)N * 64 * 2);
    unsigned short* v = (unsigned short*)alloc((size_t)N * 64 * 2);
    float* h2 = (float*)u;   // alias: u,v dead after agg_kernel
    unsigned short* agg = (unsigned short*)alloc((size_t)N * 192 * 2);
    float* csr_eig = (float*)alloc((size_t)E * 4);
    int*   csr_src = (int*)alloc((size_t)E * 4);
    // contiguous zero region: deg, absum, sege, bn_buf
    char* zero_base = w + off;
    int*   deg    = (int*)alloc((size_t)N * 4);
    float* absum  = (float*)alloc((size_t)N * 4);
    float* sege   = (float*)alloc((size_t)N * 4);
    float* bn_buf = (float*)alloc(128 * 4);
    size_t zero_bytes = (size_t)((char*)(bn_buf + 128) - zero_base);
    int* offs   = (int*)alloc((size_t)N * 4);
    int* cursor = (int*)alloc((size_t)N * 4);
    int nb = (N + 255) / 256;
    int* bsum  = (int*)alloc((size_t)nb * 4);
    int* bscan = (int*)alloc((size_t)nb * 4);
    float* w2t = (float*)alloc(64 * 256 * 4);
    (void)ws_size; (void)n_in; (void)out_size;

    hipMemsetAsync(zero_base, 0, zero_bytes, stream);

    int egrid = (E + 255) / 256;
    edge_stats_kernel<<<egrid, 256, 0, stream>>>(dst, eig, deg, absum, sege, E);
    block_reduce_kernel<<<nb, 256, 0, stream>>>(deg, bsum, N);
    scan_bsums_kernel<<<1, 1024, 0, stream>>>(bsum, bscan, nb);
    block_scan_kernel<<<nb, 256, 0, stream>>>(deg, bscan, offs, cursor, N);
    csr_scatter_kernel<<<egrid, 256, 0, stream>>>(src, dst, eig, cursor, csr_src, csr_eig, E);

    int ntiles = (N + 63) / 64;
    uv_kernel<<<ntiles, 256, 0, stream>>>(h, W1, b1, u, v, N);
    w2t_kernel<<<64, 256, 0, stream>>>(W2, w2t);

    int agrid = ((size_t)N * 64 + 255) / 256;
    agg_kernel<<<agrid, 256, 0, stream>>>(u, v, h, offs, deg, absum, sege,
                                          csr_src, csr_eig, agg, N);

    post_gemm_kernel<<<(N + 63) / 64, 256, 0, stream>>>(h, agg, w2t, b2, snorm,
                                                        h2, bn_buf, N);

    int fgrid = (N * 16 + 255) / 256;
    bn_final_kernel<<<fgrid, 256, 0, stream>>>(h, h2, bn_buf, gamma, beta, out, N, 1.0f / (float)N);
}

// Round 3
// 389.682 us; speedup vs baseline: 1.9910x; 1.4630x over previous
//
#include <hip/hip_runtime.h>
#include <math.h>

__device__ __forceinline__ float bf2f(unsigned short s) {
    return __uint_as_float(((unsigned)s) << 16);
}
__device__ __forceinline__ unsigned short f2bf(float f) {
    unsigned u = __float_as_uint(f);
    unsigned r = (u + 0x7fffu + ((u >> 16) & 1u)) >> 16;   // RNE
    return (unsigned short)r;
}

// ---------------- K1: per-edge rank + deg histogram (single atomic) ----------------
__global__ __launch_bounds__(256) void edge_rank_kernel(
    const int* __restrict__ dst, int* __restrict__ cursor, int* __restrict__ rank, int E)
{
    int e = blockIdx.x * 256 + threadIdx.x;
    if (e < E) {
        rank[e] = atomicAdd(&cursor[dst[e]], 1);
    }
}

// ---------------- K2a: per-block reduce of deg ----------------
__global__ __launch_bounds__(256) void block_reduce_kernel(
    const int* __restrict__ deg, int* __restrict__ bsum, int N)
{
    __shared__ int sd[256];
    int t = threadIdx.x;
    int i = blockIdx.x * 256 + t;
    sd[t] = (i < N) ? deg[i] : 0;
    __syncthreads();
    for (int s = 128; s > 0; s >>= 1) {
        if (t < s) sd[t] += sd[t + s];
        __syncthreads();
    }
    if (t == 0) bsum[blockIdx.x] = sd[0];
}

// ---------------- K2b: scan block sums (single block) ----------------
__global__ __launch_bounds__(1024) void scan_bsums_kernel(
    const int* __restrict__ bsum, int* __restrict__ bscan, int nb)
{
    __shared__ int sd[1024];
    int t = threadIdx.x;
    int own = (t < nb) ? bsum[t] : 0;
    sd[t] = own;
    __syncthreads();
    for (int off = 1; off < 1024; off <<= 1) {
        int v = (t >= off) ? sd[t - off] : 0;
        __syncthreads();
        sd[t] += v;
        __syncthreads();
    }
    if (t < nb) bscan[t] = sd[t] - own;   // exclusive prefix
}

// ---------------- K2c: per-block exclusive scan -> offsets ----------------
__global__ __launch_bounds__(256) void block_scan_kernel(
    const int* __restrict__ deg, const int* __restrict__ bscan,
    int* __restrict__ offs, int N)
{
    __shared__ int sd[256];
    int t = threadIdx.x;
    int i = blockIdx.x * 256 + t;
    int myv = (i < N) ? deg[i] : 0;
    sd[t] = myv;
    __syncthreads();
    for (int off = 1; off < 256; off <<= 1) {
        int v = (t >= off) ? sd[t - off] : 0;
        __syncthreads();
        sd[t] += v;
        __syncthreads();
    }
    if (i < N) {
        offs[i] = sd[t] - myv + bscan[blockIdx.x];
    }
}

// ---------------- K3: scatter edges into CSR (no atomics, packed 8B) ----------------
__global__ __launch_bounds__(256) void csr_scatter_kernel(
    const int* __restrict__ src, const int* __restrict__ dst, const float* __restrict__ eig,
    const int* __restrict__ rank, const int* __restrict__ offs,
    int2* __restrict__ csr, int E)
{
    int e = blockIdx.x * 256 + threadIdx.x;
    if (e < E) {
        int dn = dst[e];
        int p = offs[dn] + rank[e];
        csr[p] = make_int2(src[e], __float_as_int(eig[e]));
    }
}

// ---------------- K4: u = h @ A^T ; v = h @ B^T + b1 (bf16 outputs) ----------------
__global__ __launch_bounds__(256) void uv_kernel(
    const float* __restrict__ h, const float* __restrict__ W1, const float* __restrict__ b1,
    unsigned short* __restrict__ u, unsigned short* __restrict__ v, int N)
{
    __shared__ float wT[64 * 128];   // wT[j*128 + c]
    __shared__ float hs[64 * 68];    // hs[n*68 + j], padded
    int t = threadIdx.x;
    for (int idx = t; idx < 64 * 128; idx += 256) {
        int j = idx >> 7, c = idx & 127;
        int d = c & 63;
        int col = (c < 64) ? j : (64 + j);
        wT[idx] = W1[d * 128 + col];
    }
    int n0 = blockIdx.x * 64;
    for (int r = 0; r < 16; ++r) {
        int idx = r * 256 + t;
        int nl = idx >> 6, j = idx & 63;
        int n = n0 + nl;
        hs[nl * 68 + j] = (n < N) ? h[(size_t)n * 64 + j] : 0.f;
    }
    __syncthreads();

    int nb = (t & 15) * 4;
    int cb = (t >> 4) * 8;
    float acc[4][8];
#pragma unroll
    for (int i = 0; i < 4; ++i)
#pragma unroll
        for (int k = 0; k < 8; ++k) acc[i][k] = 0.f;

    for (int j = 0; j < 64; ++j) {
        float wv[8];
#pragma unroll
        for (int k = 0; k < 8; ++k) wv[k] = wT[j * 128 + cb + k];
#pragma unroll
        for (int i = 0; i < 4; ++i) {
            float hv = hs[(nb + i) * 68 + j];
#pragma unroll
            for (int k = 0; k < 8; ++k) acc[i][k] = fmaf(hv, wv[k], acc[i][k]);
        }
    }

    bool isV = (cb >= 64);
    int dbase = cb & 63;
#pragma unroll
    for (int i = 0; i < 4; ++i) {
        int n = n0 + nb + i;
        if (n < N) {
            union { unsigned short s[8]; uint4 v4; } pk;
            if (!isV) {
#pragma unroll
                for (int k = 0; k < 8; ++k) pk.s[k] = f2bf(acc[i][k]);
                *(uint4*)(u + (size_t)n * 64 + dbase) = pk.v4;
            } else {
#pragma unroll
                for (int k = 0; k < 8; ++k) pk.s[k] = f2bf(acc[i][k] + b1[dbase + k]);
                *(uint4*)(v + (size_t)n * 64 + dbase) = pk.v4;
            }
        }
    }
}

// ---------------- K4b: W2 transpose -> w2t[k][d] ----------------
__global__ __launch_bounds__(256) void w2t_kernel(
    const float* __restrict__ W2, float* __restrict__ w2t)
{
    int idx = blockIdx.x * 256 + threadIdx.x;
    if (idx < 64 * 256) {
        int d = idx >> 8, k = idx & 255;
        w2t[k * 64 + d] = W2[idx];
    }
}

// ---------------- K5: aggregation, one wave per node ----------------
__global__ __launch_bounds__(256) void agg_kernel(
    const unsigned short* __restrict__ u, const unsigned short* __restrict__ v,
    const float* __restrict__ h,
    const int* __restrict__ offs, const int* __restrict__ degi,
    const int2* __restrict__ csr,
    unsigned short* __restrict__ agg, int N)
{
    int gw = (blockIdx.x * 256 + threadIdx.x) >> 6;
    int lane = threadIdx.x & 63;
    int n = __builtin_amdgcn_readfirstlane(gw);
    if (n >= N) return;
    int beg = offs[n];
    int dn = degi[n];

    float accs = 0.f, accd = 0.f, accm = -3.402823466e38f;
    float pa = 0.f, ps = 0.f;   // per-lane partials for absum / sege
    for (int i0 = 0; i0 < dn; i0 += 64) {
        int cnt = min(dn - i0, 64);
        int idxv = 0; float wvv = 0.f;
        if (lane < cnt) {
            int2 rec = csr[beg + i0 + lane];
            idxv = rec.x;
            wvv = __int_as_float(rec.y);
        }
        pa += fabsf(wvv);
        ps += wvv;
        int j = 0;
        for (; j + 4 <= cnt; j += 4) {
            int s0 = __shfl(idxv, j), s1 = __shfl(idxv, j + 1);
            int s2 = __shfl(idxv, j + 2), s3 = __shfl(idxv, j + 3);
            float w0 = __shfl(wvv, j), w1 = __shfl(wvv, j + 1);
            float w2_ = __shfl(wvv, j + 2), w3 = __shfl(wvv, j + 3);
            float u0 = bf2f(u[(size_t)s0 * 64 + lane]);
            float u1 = bf2f(u[(size_t)s1 * 64 + lane]);
            float u2 = bf2f(u[(size_t)s2 * 64 + lane]);
            float u3 = bf2f(u[(size_t)s3 * 64 + lane]);
            accs += (u0 + u1) + (u2 + u3);
            accm = fmaxf(accm, fmaxf(fmaxf(u0, u1), fmaxf(u2, u3)));
            accd = fmaf(w0, u0, fmaf(w1, u1, fmaf(w2_, u2, fmaf(w3, u3, accd))));
        }
        for (; j < cnt; ++j) {
            int s0 = __shfl(idxv, j);
            float w0 = __shfl(wvv, j);
            float u0 = bf2f(u[(size_t)s0 * 64 + lane]);
            accs += u0;
            accm = fmaxf(accm, u0);
            accd = fmaf(w0, u0, accd);
        }
    }
    // wave-reduce pa (absum) and ps (sege) across 64 lanes
#pragma unroll
    for (int w = 1; w < 64; w <<= 1) {
        pa += __shfl_xor(pa, w);
        ps += __shfl_xor(ps, w);
    }
    float inv_ab = 1.f / (pa + 1e-8f);
    float segw = ps * inv_ab;

    float vl = bf2f(v[(size_t)n * 64 + lane]);
    float hl = h[(size_t)n * 64 + lane];
    float fdeg = (float)dn;
    float mean = (accs + fdeg * vl) / fmaxf(fdeg, 1.f);
    float amax = (dn > 0) ? (accm + vl) : 0.f;
    float adir = fabsf(fmaf(accd, inv_ab, segw * (vl - hl)));
    size_t base = (size_t)n * 192;
    agg[base + lane]       = f2bf(mean);
    agg[base + 64 + lane]  = f2bf(amax);
    agg[base + 128 + lane] = f2bf(adir);
}

// ---------------- K6: posttrans GEMM-T + BN partials ----------------
__global__ __launch_bounds__(256) void post_gemm_kernel(
    const float* __restrict__ h, const unsigned short* __restrict__ agg,
    const float* __restrict__ w2t, const float* __restrict__ b2,
    const float* __restrict__ snorm, float* __restrict__ h2,
    float* __restrict__ bn_buf, int N)
{
    __shared__ float hcS[64 * 65];   // [k][node], stride 65 (conflict-free)
    int tid = threadIdx.x;
    int node = tid & 63;
    int q = __builtin_amdgcn_readfirstlane(tid >> 6);
    int n0 = blockIdx.x * 64;
    int n = n0 + node;
    float acc[16];
#pragma unroll
    for (int i = 0; i < 16; ++i) acc[i] = 0.f;

    for (int c = 0; c < 4; ++c) {
        if (c == 0) {
            for (int it = 0; it < 4; ++it) {
                int idx = it * 256 + tid;     // 0..1023
                int r = idx >> 4, c4 = idx & 15;
                int nn = n0 + r;
                float4 val = make_float4(0.f, 0.f, 0.f, 0.f);
                if (nn < N) val = *(const float4*)(h + (size_t)nn * 64 + c4 * 4);
                int kk = c4 * 4;
                hcS[(kk + 0) * 65 + r] = val.x;
                hcS[(kk + 1) * 65 + r] = val.y;
                hcS[(kk + 2) * 65 + r] = val.z;
                hcS[(kk + 3) * 65 + r] = val.w;
            }
        } else {
            for (int it = 0; it < 2; ++it) {
                int idx = it * 256 + tid;     // 0..511
                int r = idx >> 3, j8 = idx & 7;
                int nn = n0 + r;
                uint4 val = make_uint4(0, 0, 0, 0);
                if (nn < N) val = *(const uint4*)(agg + (size_t)nn * 192 + (c - 1) * 64 + j8 * 8);
                unsigned short* ps = (unsigned short*)&val;
                int kk = j8 * 8;
#pragma unroll
                for (int m = 0; m < 8; ++m)
                    hcS[(kk + m) * 65 + r] = bf2f(ps[m]);
            }
        }
        __syncthreads();
        const float* wbase = w2t + c * 64 * 64 + q * 16;
        for (int k = 0; k < 64; ++k) {
            float hv = hcS[k * 65 + node];
            const float* wr = wbase + k * 64;
#pragma unroll
            for (int i = 0; i < 16; ++i)
                acc[i] = fmaf(wr[i], hv, acc[i]);
        }
        __syncthreads();
    }

    float sn = (n < N) ? snorm[n] : 0.f;
#pragma unroll
    for (int i = 0; i < 16; ++i) acc[i] = (acc[i] + b2[q * 16 + i]) * sn;

    if (n < N) {
#pragma unroll
        for (int i = 0; i < 4; ++i) {
            float4 o = make_float4(acc[i * 4], acc[i * 4 + 1], acc[i * 4 + 2], acc[i * 4 + 3]);
            *(float4*)(h2 + (size_t)n * 64 + q * 16 + i * 4) = o;
        }
    }

#pragma unroll
    for (int i = 0; i < 16; ++i) hcS[(q * 16 + i) * 65 + node] = acc[i];
    __syncthreads();
    if (tid < 64) {
        float s1 = 0.f, s2 = 0.f;
        for (int r = 0; r < 64; ++r) {
            float x = hcS[tid * 65 + r];
            s1 += x;
            s2 = fmaf(x, x, s2);
        }
        atomicAdd(&bn_buf[tid], s1);
        atomicAdd(&bn_buf[64 + tid], s2);
    }
}

// ---------------- K7: BN normalize + relu + residual ----------------
__global__ __launch_bounds__(256) void bn_final_kernel(
    const float* __restrict__ h, const float* __restrict__ h2,
    const float* __restrict__ bn_buf, const float* __restrict__ gamma,
    const float* __restrict__ beta, float* __restrict__ out, int N, float invN)
{
    int idx = blockIdx.x * 256 + threadIdx.x;  // one float4 per thread
    int total4 = N * 16;
    if (idx >= total4) return;
    int base = idx * 4;
    int d0 = base & 63;
    const float4 a = *(const float4*)(h2 + base);
    const float4 hh = *(const float4*)(h + base);
    float r[4] = {a.x, a.y, a.z, a.w};
    float hv[4] = {hh.x, hh.y, hh.z, hh.w};
    float o[4];
#pragma unroll
    for (int k = 0; k < 4; ++k) {
        int d = d0 + k;
        float mu = bn_buf[d] * invN;
        float var = bn_buf[64 + d] * invN - mu * mu;
        float rstd = rsqrtf(var + 1e-5f);
        float x = (r[k] - mu) * rstd * gamma[d] + beta[d];
        o[k] = hv[k] + fmaxf(x, 0.f);
    }
    float4 ov = {o[0], o[1], o[2], o[3]};
    *(float4*)(out + base) = ov;
}

// ---------------- launch ----------------
extern "C" void kernel_launch(void* const* d_in, const int* in_sizes, int n_in,
                              void* d_out, int out_size, void* d_ws, size_t ws_size,
                              hipStream_t stream)
{
    const float* h     = (const float*)d_in[0];
    const float* eig   = (const float*)d_in[1];
    const float* snorm = (const float*)d_in[2];
    const int*   src   = (const int*)d_in[3];
    const int*   dst   = (const int*)d_in[4];
    const float* W1    = (const float*)d_in[5];
    const float* b1    = (const float*)d_in[6];
    const float* W2    = (const float*)d_in[7];
    const float* b2    = (const float*)d_in[8];
    const float* gamma = (const float*)d_in[9];
    const float* beta  = (const float*)d_in[10];
    float* out = (float*)d_out;

    const int N = in_sizes[2];
    const int E = in_sizes[1];

    // ---- workspace layout (256B aligned slices) ----
    char* w = (char*)d_ws;
    size_t off = 0;
    auto alloc = [&](size_t bytes) -> char* {
        char* p = w + off;
        off += (bytes + 255) & ~size_t(255);
        return p;
    };
    // u,v bf16 contiguous (25.6MB); h2 fp32 aliases the same region after agg
    unsigned short* u = (unsigned short*)alloc((size_t)N * 64 * 2);
    unsigned short* v = (unsigned short*)alloc((size_t)N * 64 * 2);
    float* h2 = (float*)u;   // alias: u,v dead after agg_kernel
    unsigned short* agg = (unsigned short*)alloc((size_t)N * 192 * 2);
    int2* csr = (int2*)alloc((size_t)E * 8);
    int*  rank = (int*)alloc((size_t)E * 4);
    // contiguous zero region: cursor (deg histogram) + bn_buf
    char* zero_base = w + off;
    int*   cursor = (int*)alloc((size_t)N * 4);   // becomes deg
    float* bn_buf = (float*)alloc(128 * 4);
    size_t zero_bytes = (size_t)((char*)(bn_buf + 128) - zero_base);
    int* offs = (int*)alloc((size_t)N * 4);
    int nb = (N + 255) / 256;
    int* bsum  = (int*)alloc((size_t)nb * 4);
    int* bscan = (int*)alloc((size_t)nb * 4);
    float* w2t = (float*)alloc(64 * 256 * 4);
    (void)ws_size; (void)n_in; (void)out_size;

    hipMemsetAsync(zero_base, 0, zero_bytes, stream);

    int egrid = (E + 255) / 256;
    edge_rank_kernel<<<egrid, 256, 0, stream>>>(dst, cursor, rank, E);
    block_reduce_kernel<<<nb, 256, 0, stream>>>(cursor, bsum, N);
    scan_bsums_kernel<<<1, 1024, 0, stream>>>(bsum, bscan, nb);
    block_scan_kernel<<<nb, 256, 0, stream>>>(cursor, bscan, offs, N);
    csr_scatter_kernel<<<egrid, 256, 0, stream>>>(src, dst, eig, rank, offs, csr, E);

    int ntiles = (N + 63) / 64;
    uv_kernel<<<ntiles, 256, 0, stream>>>(h, W1, b1, u, v, N);
    w2t_kernel<<<64, 256, 0, stream>>>(W2, w2t);

    int agrid = ((size_t)N * 64 + 255) / 256;
    agg_kernel<<<agrid, 256, 0, stream>>>(u, v, h, offs, cursor, csr, agg, N);

    post_gemm_kernel<<<(N + 63) / 64, 256, 0, stream>>>(h, agg, w2t, b2, snorm,
                                                        h2, bn_buf, N);

    int fgrid = (N * 16 + 255) / 256;
    bn_final_kernel<<<fgrid, 256, 0, stream>>>(h, h2, bn_buf, gamma, beta, out, N, 1.0f / (float)N);
}